// Round 1
// baseline (92.847 us; speedup 1.0000x reference)
//
#include <hip/hip_runtime.h>

namespace {

typedef float v2f __attribute__((ext_vector_type(2)));

constexpr int T_LEN = 262144;   // samples per batch
constexpr int NF    = 1024;     // frames per batch

// Sum x across each quad of lanes (4 overlap slots) with two DPP quad_perm
// adds: xor1 = perm[1,0,3,2] = 0xB1, xor2 = perm[2,3,0,1] = 0x4E. No LDS.
__device__ __forceinline__ float qsum(float x) {
    x += __int_as_float(__builtin_amdgcn_update_dpp(
             0, __float_as_int(x), 0xB1, 0xF, 0xF, true));
    x += __int_as_float(__builtin_amdgcn_update_dpp(
             0, __float_as_int(x), 0x4E, 0xF, 0xF, true));
    return x;
}

template <bool CK>
__device__ __forceinline__ void ld4(const float* __restrict__ exb, int xi,
                                    float4 (&buf)[4]) {
    #pragma unroll
    for (int q = 0; q < 4; ++q) {
        const int idx = xi + q * 4;
        if (CK) {   // only wave 0 of each batch can touch idx<0; upper bound proven
            float4 v = make_float4(0.f, 0.f, 0.f, 0.f);
            if (idx >= 0) v = *(const float4*)(exb + idx);
            buf[q] = v;
        } else {
            buf[q] = *(const float4*)(exb + idx);
        }
    }
}

// 4 samples of order-22 IIR (transposed DF-II), state packed (s[j], s[j+11])
// so the delay-line shift maps onto v_pk_fma_f32. 13 VALU inst / sample.
__device__ __forceinline__ void iir4(const float4& x4, v2f (&sv)[11],
                                     const v2f (&mav)[11], float gv,
                                     float (&yo)[4]) {
    const float xv[4] = {x4.x, x4.y, x4.z, x4.w};
    #pragma unroll
    for (int u = 0; u < 4; ++u) {
        float y   = fmaf(gv, xv[u], sv[0].x);
        float s11 = sv[0].y;
        v2f yy = (v2f){y, y};
        #pragma unroll
        for (int j = 0; j < 10; ++j)
            sv[j] = __builtin_elementwise_fma(mav[j], yy, sv[j + 1]);
        sv[10].x = fmaf(mav[10].x, y, s11);
        sv[10].y = mav[10].y * y;
        yo[u] = y;
    }
}

__device__ __forceinline__ void proc16w(const float4 (&buf)[4], v2f (&sv)[11],
                                        const v2f (&mav)[11], float gv) {
    float yd[4];
    #pragma unroll
    for (int q = 0; q < 4; ++q) iir4(buf[q], sv, mav, gv, yd);
}

// 16 output samples: IIR + per-lane hann weight (one v_cos each) + quad DPP
// reduction + predicated float4 store (lane kk owns quarter kk of the block).
template <bool EDGE>
__device__ __forceinline__ void proc16o(const float4 (&buf)[4], v2f (&sv)[11],
                                        const v2f (&mav)[11], float gv,
                                        float& rev, float cA, float cB,
                                        bool st, float* __restrict__ outp) {
    #pragma unroll
    for (int q = 0; q < 4; ++q) {
        float y[4];
        iir4(buf[q], sv, mav, gv, y);
        float o[4];
        #pragma unroll
        for (int u = 0; u < 4; ++u) {
            float c = __builtin_amdgcn_cosf(rev);   // cos(2*pi*rev), rev in [0,1)
            rev += (1.0f / 1024.0f);
            float wl = fmaf(cA, c, cB);             // scaled hann * validity mask
            float v  = wl * y[u];
            if (EDGE) {
                o[u] = qsum(v) * __builtin_amdgcn_rcpf(qsum(wl));
            } else {
                o[u] = qsum(v);   // interior: wsum == 2, 0.25 scale folded in cA/cB
            }
        }
        if (st) *(float4*)(outp + q * 4) = make_float4(o[0], o[1], o[2], o[3]);
    }
}

// Per batch: 2048 output blocks of 128 samples (i = 3..2050; out base i*128-384
// tiles [0, 262144) exactly). Quad slot kk reads frame f = (i>>1)-kk starting
// 128 warm samples (zero-state truncation, validated absmax ~0.008) before its
// 128 output samples. No LDS, no barriers, single-pass.
//
// Software pipeline: FOUR register buffers (A,B,C,D), loads issued 3 sub-blocks
// (~1300+ issue-cycles) ahead of consumption, 16 loads outstanding per wave.
// At 2 waves/SIMD this is the only latency-hiding available; the previous
// 2-buffer ping-pong gave only ~1 sub-block (~450 cyc) of slack vs post-fill
// (L3-evicted, writeback-contended) memory latency.
__global__ __launch_bounds__(64, 2)
void lpc_ola_kernel(const float* __restrict__ ex,
                    const float* __restrict__ gain,
                    const float* __restrict__ a,
                    float* __restrict__ out)
{
    const int lane = threadIdx.x;
    const int w    = blockIdx.x;
    const int wloc = w & 127;
    const bool chk  = (wloc == 0);
    const bool edge = (wloc == 0) | (wloc == 127);

    const int kk = lane & 3;          // overlap slot (within quad)
    const int jl = lane >> 2;         // task-in-wave
    const int tau = w * 16 + jl;
    const int b  = tau >> 11;
    const int i  = (tau & 2047) + 3;
    const int fi = i >> 1;
    const int f  = fi - kk;
    const bool fv = (unsigned)f < (unsigned)NF;
    const int fc = fv ? f : 0;
    const float mval = fv ? 1.f : 0.f;
    const float gv   = fv ? gain[b * NF + fc] : 0.f;  // y=0 for invalid slots

    v2f mav[11];
    {
        const float2* ap = (const float2*)(a + (size_t)(b * NF + fc) * 22);
        float man[22];
        #pragma unroll
        for (int j = 0; j < 11; ++j) {
            float2 t = ap[j];
            man[2 * j] = -t.x; man[2 * j + 1] = -t.y;
        }
        #pragma unroll
        for (int j = 0; j < 11; ++j) mav[j] = (v2f){man[j], man[j + 11]};
    }
    v2f sv[11];
    #pragma unroll
    for (int j = 0; j < 11; ++j) sv[j] = (v2f){0.f, 0.f};

    const float* exb = ex + (size_t)b * T_LEN;
    int xi = i * 128 - 512;                         // first warm sample (kk-indep)
    const int m0k = kk * 256 + ((i & 1) << 7);      // frame-local idx of out sample 0
    float rev = (float)m0k * (1.0f / 1024.0f);
    const float scale = edge ? 0.5f : 0.25f;
    const float cA = -scale * mval, cB = scale * mval;
    float* outp0 = out + (size_t)b * T_LEN + (i * 128 - 384);

    float4 A[4], B[4], C[4], D[4];
    // ---- prologue: fill all 4 pipeline stages (sub-blocks 0..3) ----
    if (chk) {
        ld4<true >(exb, xi, A); xi += 16;
        ld4<true >(exb, xi, B); xi += 16;
        ld4<true >(exb, xi, C); xi += 16;
        ld4<true >(exb, xi, D); xi += 16;
    } else {
        ld4<false>(exb, xi, A); xi += 16;
        ld4<false>(exb, xi, B); xi += 16;
        ld4<false>(exb, xi, C); xi += 16;
        ld4<false>(exb, xi, D); xi += 16;
    }

    // ---- warm: 128 samples = 8 sub-blocks, refill 4 sub-blocks ahead ----
    // it=0: consume sb0..3, load sb4..7; it=1: consume sb4..7, load sb8..11.
    #pragma unroll 1
    for (int it = 0; it < 2; ++it) {
        proc16w(A, sv, mav, gv);
        if (chk) ld4<true>(exb, xi, A); else ld4<false>(exb, xi, A);
        xi += 16;
        proc16w(B, sv, mav, gv);
        if (chk) ld4<true>(exb, xi, B); else ld4<false>(exb, xi, B);
        xi += 16;
        proc16w(C, sv, mav, gv);
        if (chk) ld4<true>(exb, xi, C); else ld4<false>(exb, xi, C);
        xi += 16;
        proc16w(D, sv, mav, gv);
        if (chk) ld4<true>(exb, xi, D); else ld4<false>(exb, xi, D);
        xi += 16;
    }
    // A..D = out sub-blocks 0..3 (sb8..11), already in flight/resident.

    // ---- out: 128 samples = 8 sub-blocks; refill sb12..15 during first 4 ----
    if (!edge) {
        #pragma unroll 1
        for (int it = 0; it < 2; ++it) {
            const int sb = it * 4;
            proc16o<false>(A, sv, mav, gv, rev, cA, cB,
                           kk == ((sb + 0) >> 1), outp0 + (sb + 0) * 16);
            if (it == 0) { ld4<false>(exb, xi, A); xi += 16; }
            proc16o<false>(B, sv, mav, gv, rev, cA, cB,
                           kk == ((sb + 1) >> 1), outp0 + (sb + 1) * 16);
            if (it == 0) { ld4<false>(exb, xi, B); xi += 16; }
            proc16o<false>(C, sv, mav, gv, rev, cA, cB,
                           kk == ((sb + 2) >> 1), outp0 + (sb + 2) * 16);
            if (it == 0) { ld4<false>(exb, xi, C); xi += 16; }
            proc16o<false>(D, sv, mav, gv, rev, cA, cB,
                           kk == ((sb + 3) >> 1), outp0 + (sb + 3) * 16);
            if (it == 0) { ld4<false>(exb, xi, D); xi += 16; }
        }
    } else {
        #pragma unroll 1
        for (int it = 0; it < 2; ++it) {
            const int sb = it * 4;
            proc16o<true>(A, sv, mav, gv, rev, cA, cB,
                          kk == ((sb + 0) >> 1), outp0 + (sb + 0) * 16);
            if (it == 0) { ld4<false>(exb, xi, A); xi += 16; }
            proc16o<true>(B, sv, mav, gv, rev, cA, cB,
                          kk == ((sb + 1) >> 1), outp0 + (sb + 1) * 16);
            if (it == 0) { ld4<false>(exb, xi, B); xi += 16; }
            proc16o<true>(C, sv, mav, gv, rev, cA, cB,
                          kk == ((sb + 2) >> 1), outp0 + (sb + 2) * 16);
            if (it == 0) { ld4<false>(exb, xi, C); xi += 16; }
            proc16o<true>(D, sv, mav, gv, rev, cA, cB,
                          kk == ((sb + 3) >> 1), outp0 + (sb + 3) * 16);
            if (it == 0) { ld4<false>(exb, xi, D); xi += 16; }
        }
    }
}

} // namespace

extern "C" void kernel_launch(void* const* d_in, const int* in_sizes, int n_in,
                              void* d_out, int out_size, void* d_ws, size_t ws_size,
                              hipStream_t stream)
{
    (void)in_sizes; (void)n_in; (void)out_size; (void)d_ws; (void)ws_size;
    const float* ex   = (const float*)d_in[0];
    const float* gain = (const float*)d_in[1];
    const float* a    = (const float*)d_in[2];
    float* out        = (float*)d_out;

    dim3 grid(2048);   // 16 batches x 2048 blocks / 16 tasks per wave
    dim3 block(64);
    hipLaunchKernelGGL(lpc_ola_kernel, grid, block, 0, stream, ex, gain, a, out);
}